// Round 18
// baseline (105.787 us; speedup 1.0000x reference)
//
#include <hip/hip_runtime.h>
#include <hip/hip_bf16.h>

// Problem sizes (fixed by the reference)
#define S_LEN 256     // sequence length (t)
#define DM    512     // d_model (k / d)
#define DR    512     // d_rnn (s)

typedef float f4 __attribute__((ext_vector_type(4)));
typedef float f2 __attribute__((ext_vector_type(2)));

// ws layout (floats):
//   xT  : [512][256]     at 0       (131072)
//   acT : f2[512][256]   at 131072  (262144)

__global__ __launch_bounds__(256) void k_transpose_x(const float* __restrict__ x,
                                                     float* __restrict__ xT) {
    __shared__ float tile[32][33];
    const int k0 = blockIdx.x * 32;
    const int t0 = blockIdx.y * 32;
    const int lx = threadIdx.x & 31;
    const int ly = threadIdx.x >> 5;
#pragma unroll
    for (int i = 0; i < 32; i += 8)
        tile[ly + i][lx] = x[(t0 + ly + i) * DM + k0 + lx];
    __syncthreads();
#pragma unroll
    for (int i = 0; i < 32; i += 8)
        xT[(k0 + ly + i) * S_LEN + t0 + lx] = tile[lx][ly + i];
}

// grid(512) x 256: block = one s-row (XCD-banded). lane = t.
// KEY: W1 row reads are forced onto the VECTOR memory path (same-address
// broadcast global_load_dwordx4) by an opaque zero VGPR in the index, so
// they ride the counted vmcnt queue together with the coalesced xT loads.
// The previous structure let the compiler scalarize W -> s_loads, whose
// UNORDERED completion forces a full lgkmcnt(0) drain every unroll batch
// (~400 cy x 64 batches ~= the mystery 25 us every phase-1 paid).
__global__ __launch_bounds__(256) void k_act(const float* __restrict__ xT,
                                             const float* __restrict__ W1,
                                             const float* __restrict__ b1,
                                             const float* __restrict__ Lam,
                                             f2* __restrict__ acT) {
    const int bx = blockIdx.x;                 // 0..511
    const int s  = (bx & 7) * 64 + (bx >> 3);  // bijective XCD s-banding
    const int t  = threadIdx.x;

    int vz;
    asm("v_mov_b32 %0, 0" : "=v"(vz));         // opaque 0 in a VGPR

    const f4* __restrict__ Wi = reinterpret_cast<const f4*>(W1 + s * DM);
    const f4* __restrict__ Wr = reinterpret_cast<const f4*>(W1 + (DR + s) * DM);
    const float* __restrict__ xb = xT + t;

    float ai = 0.f, ar = 0.f;

#pragma unroll 4
    for (int kq = 0; kq < DM / 4; ++kq) {
        const f4 wi = Wi[kq + vz];             // vector broadcast load (vmcnt)
        const f4 wr = Wr[kq + vz];
        const float x0 = xb[(4 * kq + 0) * S_LEN];   // coalesced (lane = t)
        const float x1 = xb[(4 * kq + 1) * S_LEN];
        const float x2 = xb[(4 * kq + 2) * S_LEN];
        const float x3 = xb[(4 * kq + 3) * S_LEN];
        ai = fmaf(x0, wi.x, ai); ai = fmaf(x1, wi.y, ai);
        ai = fmaf(x2, wi.z, ai); ai = fmaf(x3, wi.w, ai);
        ar = fmaf(x0, wr.x, ar); ar = fmaf(x1, wr.y, ar);
        ar = fmaf(x2, wr.z, ar); ar = fmaf(x3, wr.w, ar);
    }

    const float pre_i = ai + b1[s];
    const float pre_r = ar + b1[DR + s];
    const float inp = 1.f / (1.f + expf(-pre_i));    // sigmoid
    const float rec = 1.f / (1.f + expf(-pre_r));    // sigmoid
    const float sof = log1pf(expf(Lam[s]));          // softplus
    const float a   = expf(-8.f * sof * rec);
    const float c   = sqrtf(fmaxf(1.f - a * a, 0.f)) * inp;
    f2 ac; ac.x = a; ac.y = c;
    acT[s * S_LEN + t] = ac;
}

// grid(256) x 256: R11's k_rec verbatim (measured 44.4 us, ~6.1 TB/s).
__global__ __launch_bounds__(256) void k_rec(const float* __restrict__ x,
                                             const float* __restrict__ state0,
                                             const f2* __restrict__ acT,
                                             f4* __restrict__ out4) {
    const int bx   = blockIdx.x;
    const int sp   = (bx & 7) * 32 + (bx >> 3);   // bijective XCD s-banding
    const int tid  = threadIdx.x;
    const int half = tid >> 7;           // 0 or 1
    const int s    = sp * 2 + half;
    const int dq   = tid & 127;          // d/4

    __shared__ f2 ac_l[2][S_LEN];        // {a, c} per (half, t)
    f2* lf = &ac_l[0][0];
    lf[tid]       = acT[sp * 2 * S_LEN + tid];
    lf[tid + 256] = acT[sp * 2 * S_LEN + tid + 256];
    __syncthreads();

    const f4* __restrict__ st4 = reinterpret_cast<const f4*>(state0);
    f4 h = st4[s * 128 + dq];

    const f4* __restrict__ x4 = reinterpret_cast<const f4*>(x);
    f4 xv = x4[dq];                      // t = 0 prefetch

#pragma unroll 4
    for (int t = 0; t < S_LEN; ++t) {
        f4 xn;
        if (t + 1 < S_LEN) xn = x4[(t + 1) * 128 + dq];
        else xn = (f4)0.f;

        const f2 ac = ac_l[half][t];               // LDS broadcast (wave-uniform)
        const float at = ac.x, ct = ac.y;
        h.x = fmaf(at, h.x, ct * xv.x);
        h.y = fmaf(at, h.y, ct * xv.y);
        h.z = fmaf(at, h.z, ct * xv.z);
        h.w = fmaf(at, h.w, ct * xv.w);

        __builtin_nontemporal_store(h, &out4[(t * DR + s) * 128 + dq]);
        xv = xn;
    }
    // final state
    out4[(S_LEN * DR) * 128 + s * 128 + dq] = h;
}

extern "C" void kernel_launch(void* const* d_in, const int* in_sizes, int n_in,
                              void* d_out, int out_size, void* d_ws, size_t ws_size,
                              hipStream_t stream) {
    const float* x      = (const float*)d_in[0];
    const float* state0 = (const float*)d_in[1];
    const float* W1     = (const float*)d_in[2];
    const float* b1     = (const float*)d_in[3];
    const float* Lam    = (const float*)d_in[4];

    float* ws  = (float*)d_ws;
    float* xT  = ws;                      // 131072 floats
    f2*    acT = (f2*)(ws + 131072);      // 131072 f2

    f4* out4 = (f4*)d_out;

    k_transpose_x<<<dim3(16, 8), 256, 0, stream>>>(x, xT);
    k_act<<<dim3(512), 256, 0, stream>>>(xT, W1, b1, Lam, acT);
    k_act<<<dim3(512), 256, 0, stream>>>(xT, W1, b1, Lam, acT);  // timing probe:
    // idempotent duplicate; k_act cost = (total - 48.4)/2 resolves phase-1
    // attribution exactly (R14 method).
    k_rec<<<dim3(256), 256, 0, stream>>>(x, state0, acT, out4);
}

// Round 19
// 80.643 us; speedup vs baseline: 1.3118x; 1.3118x over previous
//
#include <hip/hip_runtime.h>
#include <hip/hip_bf16.h>

// Problem sizes (fixed by the reference)
#define S_LEN 256     // sequence length (t)
#define DM    512     // d_model (k / d)
#define DR    512     // d_rnn (s)

typedef float f4 __attribute__((ext_vector_type(4)));
typedef float f2 __attribute__((ext_vector_type(2)));

// ws layout (floats):
//   xT   : [512][256]        at 0        (131072)
//   part : [4][1024][256]    at 131072   (1048576)
//   acT  : f2[512][256]      at 1179648  (262144)

__global__ __launch_bounds__(256) void k_transpose_x(const float* __restrict__ x,
                                                     float* __restrict__ xT) {
    __shared__ float tile[32][33];
    const int k0 = blockIdx.x * 32;
    const int t0 = blockIdx.y * 32;
    const int lx = threadIdx.x & 31;
    const int ly = threadIdx.x >> 5;
#pragma unroll
    for (int i = 0; i < 32; i += 8)
        tile[ly + i][lx] = x[(t0 + ly + i) * DM + k0 + lx];
    __syncthreads();
#pragma unroll
    for (int i = 0; i < 32; i += 8)
        xT[(k0 + ly + i) * S_LEN + t0 + lx] = tile[lx][ly + i];
}

// grid(256) = 64 s-tiles x 4 k-quarters. Block (st, kq): computes partial dots
// for 16 W rows {st*8..st*8+8} u {512+st*8..} over k in [kq*128, kq*128+128),
// all 256 t (lane = t, coalesced xT reads). TRAFFIC is the point: each block
// reads a 128 KB x-slice (not the full 512 KB) -> 32 MB total vs the 128-256MB
// every previous phase-1 paid (which was the hidden ~25-30 us: L2/L3-BW-bound).
// x value reused 16x from registers; W via same-address broadcast f4 loads
// (vz keeps them on the vector path, counted vmcnt).
__global__ __launch_bounds__(256) void k_gemm(const float* __restrict__ xT,
                                              const float* __restrict__ W1,
                                              float* __restrict__ part) {
    const int bx = blockIdx.x;        // 0..255
    const int st = bx >> 2;           // s-tile 0..63
    const int kq = bx & 3;            // k-quarter 0..3
    const int t  = threadIdx.x;

    int vz;
    asm("v_mov_b32 %0, 0" : "=v"(vz));   // opaque 0: force vector-path W loads

    const f4* __restrict__ W4 = reinterpret_cast<const f4*>(W1);
    const float* __restrict__ xb = xT + kq * 128 * S_LEN + t;

    float acc[16];
#pragma unroll
    for (int j = 0; j < 16; ++j) acc[j] = 0.f;

#pragma unroll 2
    for (int kk = 0; kk < 32; ++kk) {         // k-quads within the quarter
        const float x0 = xb[(4 * kk + 0) * S_LEN];
        const float x1 = xb[(4 * kk + 1) * S_LEN];
        const float x2 = xb[(4 * kk + 2) * S_LEN];
        const float x3 = xb[(4 * kk + 3) * S_LEN];
#pragma unroll
        for (int j = 0; j < 16; ++j) {
            const int row = (j < 8) ? (st * 8 + j) : (DR + st * 8 + (j - 8));
            const f4 w = W4[row * 128 + kq * 32 + kk + vz];  // L1 broadcast
            acc[j] = fmaf(x0, w.x, acc[j]);
            acc[j] = fmaf(x1, w.y, acc[j]);
            acc[j] = fmaf(x2, w.z, acc[j]);
            acc[j] = fmaf(x3, w.w, acc[j]);
        }
    }

    float* __restrict__ pb = part + kq * (1024 * 256);
#pragma unroll
    for (int j = 0; j < 16; ++j) {
        const int row = (j < 8) ? (st * 8 + j) : (DR + st * 8 + (j - 8));
        pb[row * 256 + t] = acc[j];           // coalesced (lane = t)
    }
}

// grid(512): s = bx, t = tid. Reduce 4 k-partials + activation epilogue -> acT.
__global__ __launch_bounds__(256) void k_act2(const float* __restrict__ part,
                                              const float* __restrict__ b1,
                                              const float* __restrict__ Lam,
                                              f2* __restrict__ acT) {
    const int s = blockIdx.x;
    const int t = threadIdx.x;
    const int P = 1024 * 256;

    const float pre_i = part[s * 256 + t]            + part[P + s * 256 + t]
                      + part[2 * P + s * 256 + t]    + part[3 * P + s * 256 + t]
                      + b1[s];
    const float pre_r = part[(DR + s) * 256 + t]         + part[P + (DR + s) * 256 + t]
                      + part[2 * P + (DR + s) * 256 + t] + part[3 * P + (DR + s) * 256 + t]
                      + b1[DR + s];

    const float inp = 1.f / (1.f + expf(-pre_i));    // sigmoid
    const float rec = 1.f / (1.f + expf(-pre_r));    // sigmoid
    const float sof = log1pf(expf(Lam[s]));          // softplus
    const float a   = expf(-8.f * sof * rec);
    const float c   = sqrtf(fmaxf(1.f - a * a, 0.f)) * inp;
    f2 ac; ac.x = a; ac.y = c;
    acT[s * S_LEN + t] = ac;
}

// grid(256) x 256: R11's k_rec verbatim (measured 44.4 us, ~6.1 TB/s y write).
__global__ __launch_bounds__(256) void k_rec(const float* __restrict__ x,
                                             const float* __restrict__ state0,
                                             const f2* __restrict__ acT,
                                             f4* __restrict__ out4) {
    const int bx   = blockIdx.x;
    const int sp   = (bx & 7) * 32 + (bx >> 3);   // bijective XCD s-banding
    const int tid  = threadIdx.x;
    const int half = tid >> 7;           // 0 or 1
    const int s    = sp * 2 + half;
    const int dq   = tid & 127;          // d/4

    __shared__ f2 ac_l[2][S_LEN];        // {a, c} per (half, t)
    f2* lf = &ac_l[0][0];
    lf[tid]       = acT[sp * 2 * S_LEN + tid];
    lf[tid + 256] = acT[sp * 2 * S_LEN + tid + 256];
    __syncthreads();

    const f4* __restrict__ st4 = reinterpret_cast<const f4*>(state0);
    f4 h = st4[s * 128 + dq];

    const f4* __restrict__ x4 = reinterpret_cast<const f4*>(x);
    f4 xv = x4[dq];                      // t = 0 prefetch

#pragma unroll 4
    for (int t = 0; t < S_LEN; ++t) {
        f4 xn;
        if (t + 1 < S_LEN) xn = x4[(t + 1) * 128 + dq];
        else xn = (f4)0.f;

        const f2 ac = ac_l[half][t];               // LDS broadcast (wave-uniform)
        const float at = ac.x, ct = ac.y;
        h.x = fmaf(at, h.x, ct * xv.x);
        h.y = fmaf(at, h.y, ct * xv.y);
        h.z = fmaf(at, h.z, ct * xv.z);
        h.w = fmaf(at, h.w, ct * xv.w);

        __builtin_nontemporal_store(h, &out4[(t * DR + s) * 128 + dq]);
        xv = xn;
    }
    // final state
    out4[(S_LEN * DR) * 128 + s * 128 + dq] = h;
}

extern "C" void kernel_launch(void* const* d_in, const int* in_sizes, int n_in,
                              void* d_out, int out_size, void* d_ws, size_t ws_size,
                              hipStream_t stream) {
    const float* x      = (const float*)d_in[0];
    const float* state0 = (const float*)d_in[1];
    const float* W1     = (const float*)d_in[2];
    const float* b1     = (const float*)d_in[3];
    const float* Lam    = (const float*)d_in[4];

    float* ws   = (float*)d_ws;
    float* xT   = ws;                       // 131072 floats
    float* part = ws + 131072;              // 1048576 floats
    f2*    acT  = (f2*)(ws + 1179648);      // 131072 f2

    f4* out4 = (f4*)d_out;

    k_transpose_x<<<dim3(16, 8), 256, 0, stream>>>(x, xT);
    k_gemm<<<dim3(256), 256, 0, stream>>>(xT, W1, part);
    k_act2<<<dim3(512), 256, 0, stream>>>(part, b1, Lam, acT);
    k_rec<<<dim3(256), 256, 0, stream>>>(x, state0, acT, out4);
}

// Round 20
// 64.791 us; speedup vs baseline: 1.6327x; 1.2447x over previous
//
#include <hip/hip_runtime.h>
#include <hip/hip_bf16.h>

// Problem sizes (fixed by the reference)
#define S_LEN 256     // sequence length (t)
#define DM    512     // d_model (k / d)
#define DR    512     // d_rnn (s)

typedef float f4 __attribute__((ext_vector_type(4)));
typedef float f2 __attribute__((ext_vector_type(2)));

// ws layout (floats):
//   xT   : [512][256]        at 0        (131072)
//   part : [4][1024][256]    at 131072   (1048576)
//   acT  : f2[512][256]      at 1179648  (262144)

__global__ __launch_bounds__(256) void k_transpose_x(const float* __restrict__ x,
                                                     float* __restrict__ xT) {
    __shared__ float tile[32][33];
    const int k0 = blockIdx.x * 32;
    const int t0 = blockIdx.y * 32;
    const int lx = threadIdx.x & 31;
    const int ly = threadIdx.x >> 5;
#pragma unroll
    for (int i = 0; i < 32; i += 8)
        tile[ly + i][lx] = x[(t0 + ly + i) * DM + k0 + lx];
    __syncthreads();
#pragma unroll
    for (int i = 0; i < 32; i += 8)
        xT[(k0 + ly + i) * S_LEN + t0 + lx] = tile[lx][ly + i];
}

// grid(1024) = 256 s-pairs x 4 k-quarters; 4 blocks/CU = 16 waves/CU (4/SIMD).
// OCCUPANCY is the change: every previous phase-1 ran at 1-2 waves/SIMD, so
// each k-batch's L2/HBM latency was fully exposed (~25-34 us for 1.7 us of
// FLOPs, invariant across 5 load-structure rewrites). With 4 waves/SIMD the
// waits interleave. Block (sp, kq): 4 W rows {2sp,2sp+1,DR+2sp,DR+2sp+1},
// k in [kq*128, kq*128+128), lane = t (coalesced xT); W wave-uniform s_loads.
__global__ __launch_bounds__(256) void k_gemm(const float* __restrict__ xT,
                                              const float* __restrict__ W1,
                                              float* __restrict__ part) {
    const int bx = blockIdx.x;        // 0..1023
    const int sp = bx >> 2;           // s-pair 0..255
    const int kq = bx & 3;            // k-quarter 0..3
    const int t  = threadIdx.x;

    const int r0 = 2 * sp, r1 = 2 * sp + 1;
    const int r2 = DR + 2 * sp, r3 = DR + 2 * sp + 1;

    const f4* __restrict__ W0 = reinterpret_cast<const f4*>(W1 + r0 * DM + kq * 128);
    const f4* __restrict__ W1p = reinterpret_cast<const f4*>(W1 + r1 * DM + kq * 128);
    const f4* __restrict__ W2 = reinterpret_cast<const f4*>(W1 + r2 * DM + kq * 128);
    const f4* __restrict__ W3 = reinterpret_cast<const f4*>(W1 + r3 * DM + kq * 128);
    const float* __restrict__ xb = xT + (kq * 128) * S_LEN + t;

    float a0 = 0.f, a1 = 0.f, a2 = 0.f, a3 = 0.f;

#pragma unroll 4
    for (int kk = 0; kk < 32; ++kk) {
        const float x0 = xb[(4 * kk + 0) * S_LEN];   // coalesced (lane = t)
        const float x1 = xb[(4 * kk + 1) * S_LEN];
        const float x2 = xb[(4 * kk + 2) * S_LEN];
        const float x3 = xb[(4 * kk + 3) * S_LEN];
        const f4 w0 = W0[kk];                        // wave-uniform -> s_load
        const f4 w1 = W1p[kk];
        const f4 w2 = W2[kk];
        const f4 w3 = W3[kk];
        a0 = fmaf(x0, w0.x, a0); a0 = fmaf(x1, w0.y, a0);
        a0 = fmaf(x2, w0.z, a0); a0 = fmaf(x3, w0.w, a0);
        a1 = fmaf(x0, w1.x, a1); a1 = fmaf(x1, w1.y, a1);
        a1 = fmaf(x2, w1.z, a1); a1 = fmaf(x3, w1.w, a1);
        a2 = fmaf(x0, w2.x, a2); a2 = fmaf(x1, w2.y, a2);
        a2 = fmaf(x2, w2.z, a2); a2 = fmaf(x3, w2.w, a2);
        a3 = fmaf(x0, w3.x, a3); a3 = fmaf(x1, w3.y, a3);
        a3 = fmaf(x2, w3.z, a3); a3 = fmaf(x3, w3.w, a3);
    }

    float* __restrict__ pb = part + kq * (1024 * 256);
    pb[r0 * 256 + t] = a0;                           // coalesced
    pb[r1 * 256 + t] = a1;
    pb[r2 * 256 + t] = a2;
    pb[r3 * 256 + t] = a3;
}

// grid(512): s = bx, t = tid. Reduce 4 k-partials + activation epilogue -> acT.
__global__ __launch_bounds__(256) void k_act2(const float* __restrict__ part,
                                              const float* __restrict__ b1,
                                              const float* __restrict__ Lam,
                                              f2* __restrict__ acT) {
    const int s = blockIdx.x;
    const int t = threadIdx.x;
    const int P = 1024 * 256;

    const float pre_i = part[s * 256 + t]            + part[P + s * 256 + t]
                      + part[2 * P + s * 256 + t]    + part[3 * P + s * 256 + t]
                      + b1[s];
    const float pre_r = part[(DR + s) * 256 + t]         + part[P + (DR + s) * 256 + t]
                      + part[2 * P + (DR + s) * 256 + t] + part[3 * P + (DR + s) * 256 + t]
                      + b1[DR + s];

    const float inp = 1.f / (1.f + expf(-pre_i));    // sigmoid
    const float rec = 1.f / (1.f + expf(-pre_r));    // sigmoid
    const float sof = log1pf(expf(Lam[s]));          // softplus
    const float a   = expf(-8.f * sof * rec);
    const float c   = sqrtf(fmaxf(1.f - a * a, 0.f)) * inp;
    f2 ac; ac.x = a; ac.y = c;
    acT[s * S_LEN + t] = ac;
}

// grid(256) x 256: R11's k_rec verbatim (measured 44.4 us, ~6.1 TB/s y write).
__global__ __launch_bounds__(256) void k_rec(const float* __restrict__ x,
                                             const float* __restrict__ state0,
                                             const f2* __restrict__ acT,
                                             f4* __restrict__ out4) {
    const int bx   = blockIdx.x;
    const int sp   = (bx & 7) * 32 + (bx >> 3);   // bijective XCD s-banding
    const int tid  = threadIdx.x;
    const int half = tid >> 7;           // 0 or 1
    const int s    = sp * 2 + half;
    const int dq   = tid & 127;          // d/4

    __shared__ f2 ac_l[2][S_LEN];        // {a, c} per (half, t)
    f2* lf = &ac_l[0][0];
    lf[tid]       = acT[sp * 2 * S_LEN + tid];
    lf[tid + 256] = acT[sp * 2 * S_LEN + tid + 256];
    __syncthreads();

    const f4* __restrict__ st4 = reinterpret_cast<const f4*>(state0);
    f4 h = st4[s * 128 + dq];

    const f4* __restrict__ x4 = reinterpret_cast<const f4*>(x);
    f4 xv = x4[dq];                      // t = 0 prefetch

#pragma unroll 4
    for (int t = 0; t < S_LEN; ++t) {
        f4 xn;
        if (t + 1 < S_LEN) xn = x4[(t + 1) * 128 + dq];
        else xn = (f4)0.f;

        const f2 ac = ac_l[half][t];               // LDS broadcast (wave-uniform)
        const float at = ac.x, ct = ac.y;
        h.x = fmaf(at, h.x, ct * xv.x);
        h.y = fmaf(at, h.y, ct * xv.y);
        h.z = fmaf(at, h.z, ct * xv.z);
        h.w = fmaf(at, h.w, ct * xv.w);

        __builtin_nontemporal_store(h, &out4[(t * DR + s) * 128 + dq]);
        xv = xn;
    }
    // final state
    out4[(S_LEN * DR) * 128 + s * 128 + dq] = h;
}

extern "C" void kernel_launch(void* const* d_in, const int* in_sizes, int n_in,
                              void* d_out, int out_size, void* d_ws, size_t ws_size,
                              hipStream_t stream) {
    const float* x      = (const float*)d_in[0];
    const float* state0 = (const float*)d_in[1];
    const float* W1     = (const float*)d_in[2];
    const float* b1     = (const float*)d_in[3];
    const float* Lam    = (const float*)d_in[4];

    float* ws   = (float*)d_ws;
    float* xT   = ws;                       // 131072 floats
    float* part = ws + 131072;              // 1048576 floats
    f2*    acT  = (f2*)(ws + 1179648);      // 131072 f2

    f4* out4 = (f4*)d_out;

    k_transpose_x<<<dim3(16, 8), 256, 0, stream>>>(x, xT);
    k_gemm<<<dim3(1024), 256, 0, stream>>>(xT, W1, part);
    k_act2<<<dim3(512), 256, 0, stream>>>(part, b1, Lam, acT);
    k_rec<<<dim3(256), 256, 0, stream>>>(x, state0, acT, out4);
}

// Round 21
// 63.816 us; speedup vs baseline: 1.6577x; 1.0153x over previous
//
#include <hip/hip_runtime.h>
#include <hip/hip_bf16.h>

// Problem sizes (fixed by the reference)
#define S_LEN 256     // sequence length (t)
#define DM    512     // d_model (k / d)
#define DR    512     // d_rnn (s)

typedef float f4 __attribute__((ext_vector_type(4)));
typedef float f2 __attribute__((ext_vector_type(2)));

// ws layout (floats):
//   xT   : [512][256]        at 0        (131072)
//   part : [8][1024][256]    at 131072   (2097152)

__global__ __launch_bounds__(256) void k_transpose_x(const float* __restrict__ x,
                                                     float* __restrict__ xT) {
    __shared__ float tile[32][33];
    const int k0 = blockIdx.x * 32;
    const int t0 = blockIdx.y * 32;
    const int lx = threadIdx.x & 31;
    const int ly = threadIdx.x >> 5;
#pragma unroll
    for (int i = 0; i < 32; i += 8)
        tile[ly + i][lx] = x[(t0 + ly + i) * DM + k0 + lx];
    __syncthreads();
#pragma unroll
    for (int i = 0; i < 32; i += 8)
        xT[(k0 + ly + i) * S_LEN + t0 + lx] = tile[lx][ly + i];
}

// grid(2048) = 256 s-pairs x 8 k-eighths; 8 blocks/CU = 32 waves/CU (8/SIMD,
// the hardware max). R20 proved phase-1 is latency-bound and scales with
// occupancy (34 us @ 8 waves/CU -> 18 us @ 16): this doubles the latency
// hiding again. Block (sp, ke): rows {2sp, 2sp+1, DR+2sp, DR+2sp+1},
// k in [ke*64, ke*64+64); lane = t (coalesced xT); W wave-uniform s_loads.
__global__ __launch_bounds__(256) void k_gemm(const float* __restrict__ xT,
                                              const float* __restrict__ W1,
                                              float* __restrict__ part) {
    const int bx = blockIdx.x;        // 0..2047
    const int sp = bx >> 3;           // s-pair 0..255
    const int ke = bx & 7;            // k-eighth 0..7
    const int t  = threadIdx.x;

    const int r0 = 2 * sp, r1 = 2 * sp + 1;
    const int r2 = DR + 2 * sp, r3 = DR + 2 * sp + 1;

    const f4* __restrict__ W0 = reinterpret_cast<const f4*>(W1 + r0 * DM + ke * 64);
    const f4* __restrict__ Wp = reinterpret_cast<const f4*>(W1 + r1 * DM + ke * 64);
    const f4* __restrict__ W2 = reinterpret_cast<const f4*>(W1 + r2 * DM + ke * 64);
    const f4* __restrict__ W3 = reinterpret_cast<const f4*>(W1 + r3 * DM + ke * 64);
    const float* __restrict__ xb = xT + (ke * 64) * S_LEN + t;

    float a0 = 0.f, a1 = 0.f, a2 = 0.f, a3 = 0.f;

#pragma unroll 4
    for (int kk = 0; kk < 16; ++kk) {
        const float x0 = xb[(4 * kk + 0) * S_LEN];   // coalesced (lane = t)
        const float x1 = xb[(4 * kk + 1) * S_LEN];
        const float x2 = xb[(4 * kk + 2) * S_LEN];
        const float x3 = xb[(4 * kk + 3) * S_LEN];
        const f4 w0 = W0[kk];                        // wave-uniform -> s_load
        const f4 w1 = Wp[kk];
        const f4 w2 = W2[kk];
        const f4 w3 = W3[kk];
        a0 = fmaf(x0, w0.x, a0); a0 = fmaf(x1, w0.y, a0);
        a0 = fmaf(x2, w0.z, a0); a0 = fmaf(x3, w0.w, a0);
        a1 = fmaf(x0, w1.x, a1); a1 = fmaf(x1, w1.y, a1);
        a1 = fmaf(x2, w1.z, a1); a1 = fmaf(x3, w1.w, a1);
        a2 = fmaf(x0, w2.x, a2); a2 = fmaf(x1, w2.y, a2);
        a2 = fmaf(x2, w2.z, a2); a2 = fmaf(x3, w2.w, a2);
        a3 = fmaf(x0, w3.x, a3); a3 = fmaf(x1, w3.y, a3);
        a3 = fmaf(x2, w3.z, a3); a3 = fmaf(x3, w3.w, a3);
    }

    float* __restrict__ pb = part + ke * (1024 * 256);
    pb[r0 * 256 + t] = a0;                           // coalesced
    pb[r1 * 256 + t] = a1;
    pb[r2 * 256 + t] = a2;
    pb[r3 * 256 + t] = a3;
}

// grid(256) x 256: R11's measured-44.4us k_rec, with the k_act2 reduction +
// activation epilogue folded into the prologue (kills one launch + the acT
// roundtrip + a separate low-occupancy kernel). Per block: 16 KB coalesced
// part reads, activation math, ac_l in LDS; then the y-stream loop verbatim.
__global__ __launch_bounds__(256) void k_rec(const float* __restrict__ x,
                                             const float* __restrict__ state0,
                                             const float* __restrict__ part,
                                             const float* __restrict__ b1,
                                             const float* __restrict__ Lam,
                                             f4* __restrict__ out4) {
    const int bx   = blockIdx.x;
    const int sp   = (bx & 7) * 32 + (bx >> 3);   // bijective XCD s-banding
    const int tid  = threadIdx.x;
    const int half = tid >> 7;           // 0 or 1
    const int s    = sp * 2 + half;
    const int dq   = tid & 127;          // d/4

    __shared__ f2 ac_l[2][S_LEN];        // {a, c} per (half, t)

    // ---- folded act: reduce 8 k-partials + activations -> ac_l ----
    const int P = 1024 * 256;
#pragma unroll
    for (int sl = 0; sl < 2; ++sl) {     // local s row (covers both halves)
        const int srow = sp * 2 + sl;
        const int tt   = tid;            // 256 threads cover all t, but we need
        if (tt < S_LEN) {                // (always true: S_LEN == 256)
            float pi = b1[srow];
            float pr = b1[DR + srow];
#pragma unroll
            for (int e = 0; e < 8; ++e) {
                pi += part[e * P + srow * 256 + tt];          // coalesced
                pr += part[e * P + (DR + srow) * 256 + tt];
            }
            const float inp = 1.f / (1.f + expf(-pi));        // sigmoid
            const float rec = 1.f / (1.f + expf(-pr));        // sigmoid
            const float sof = log1pf(expf(Lam[srow]));        // softplus
            const float a   = expf(-8.f * sof * rec);
            const float c   = sqrtf(fmaxf(1.f - a * a, 0.f)) * inp;
            f2 ac; ac.x = a; ac.y = c;
            ac_l[sl][tt] = ac;
        }
    }

    const f4* __restrict__ st4 = reinterpret_cast<const f4*>(state0);
    f4 h = st4[s * 128 + dq];

    const f4* __restrict__ x4 = reinterpret_cast<const f4*>(x);
    f4 xv = x4[dq];                      // t = 0 prefetch

    __syncthreads();                     // ac_l ready

#pragma unroll 4
    for (int t = 0; t < S_LEN; ++t) {
        f4 xn;
        if (t + 1 < S_LEN) xn = x4[(t + 1) * 128 + dq];
        else xn = (f4)0.f;

        const f2 ac = ac_l[half][t];               // LDS broadcast (wave-uniform)
        const float at = ac.x, ct = ac.y;
        h.x = fmaf(at, h.x, ct * xv.x);
        h.y = fmaf(at, h.y, ct * xv.y);
        h.z = fmaf(at, h.z, ct * xv.z);
        h.w = fmaf(at, h.w, ct * xv.w);

        __builtin_nontemporal_store(h, &out4[(t * DR + s) * 128 + dq]);
        xv = xn;
    }
    // final state
    out4[(S_LEN * DR) * 128 + s * 128 + dq] = h;
}

extern "C" void kernel_launch(void* const* d_in, const int* in_sizes, int n_in,
                              void* d_out, int out_size, void* d_ws, size_t ws_size,
                              hipStream_t stream) {
    const float* x      = (const float*)d_in[0];
    const float* state0 = (const float*)d_in[1];
    const float* W1     = (const float*)d_in[2];
    const float* b1     = (const float*)d_in[3];
    const float* Lam    = (const float*)d_in[4];

    float* ws   = (float*)d_ws;
    float* xT   = ws;                       // 131072 floats
    float* part = ws + 131072;              // 2097152 floats

    f4* out4 = (f4*)d_out;

    k_transpose_x<<<dim3(16, 8), 256, 0, stream>>>(x, xT);
    k_gemm<<<dim3(2048), 256, 0, stream>>>(xT, W1, part);
    k_rec<<<dim3(256), 256, 0, stream>>>(x, state0, part, b1, Lam, out4);
}